// Round 11
// baseline (487.871 us; speedup 1.0000x reference)
//
#include <hip/hip_runtime.h>

typedef __bf16 bf16x8 __attribute__((ext_vector_type(8)));
typedef float f32x4 __attribute__((ext_vector_type(4)));
typedef unsigned short u16x8 __attribute__((ext_vector_type(8)));
typedef int i32x4 __attribute__((ext_vector_type(4)));

#define M_TOT 8192
#define K_TOT 4096
#define N_TOT 4096
#define BM 256
#define BN 256
#define BK 64
#define NT (K_TOT / BK)   // 64

__device__ __forceinline__ unsigned short f2bf(float f) {
  union { float f; unsigned int u; } v; v.f = f;
  unsigned int u = v.u;
  return (unsigned short)((u + 0x7FFFu + ((u >> 16) & 1u)) >> 16);  // RNE
}

// weight[o][i] = bf16(codebook[o, indices[o,i]]); one thread = 8 contiguous elems
__global__ __launch_bounds__(256) void prep(const float* __restrict__ cb,
                                            const int* __restrict__ idx,
                                            unsigned short* __restrict__ Wb) {
  size_t base = ((size_t)blockIdx.x * 256 + threadIdx.x) * 8;
  const float* crow = cb + ((base >> 12) << 8);  // row = base/4096, 256 floats/row
  i32x4 i0 = *(const i32x4*)(idx + base);
  i32x4 i1 = *(const i32x4*)(idx + base + 4);
  u16x8 o;
#pragma unroll
  for (int j = 0; j < 4; ++j) { o[j] = f2bf(crow[i0[j]]); o[4 + j] = f2bf(crow[i1[j]]); }
  *(u16x8*)(Wb + base) = o;
}

#define GLDS16(g, l)                                                      \
  __builtin_amdgcn_global_load_lds(                                       \
      (__attribute__((address_space(1))) void*)(g),                       \
      (__attribute__((address_space(3))) void*)(l), 16, 0, 0)

// ============================================================================
// EXACT R4 tile schedule (measured optimum: 227.5us, MfmaUtil 54.5, 0 confl)
// with A staged from X (f32) via reg: global_load_dwordx4 x8 at tile head ->
// f2bf cvt -> swizzled ds_write_b128 x4 at mid-tile. Eliminates the X half of
// prep (134MB read + 67MB write off the critical path).
// Per-thread A cover: row = tid>>1 (256 rows), k-half = tid&1 (32 f32).
// LDS A layout unchanged: lds[r*128 + (col2B ^ ((r&7)<<4))] -- we control
// both write and read side (rule 21: both-sides-or-neither).
// vm FIFO per tile t: [B(t+1)4][A(t+1)8][B(t+2)4]. Mid vmcnt(2) (after
// B(t+2)h0 issue) retires B(t+1)+A(t+1), leaves B(t+2)h0 in flight; cvt+
// ds_write follow; end lgkm0+barrier makes writes visible (writes aged 2
// MFMA clusters by then). B(t) reads retired at t-1's mid vmcnt ✓.
// A ds_write target = other buffer's A region, LDS-dead since t-1 end ✓.
// ============================================================================
__global__ __launch_bounds__(512, 2) void gemm8(const float* __restrict__ X,
                                                const unsigned short* __restrict__ B,
                                                const float* __restrict__ bias,
                                                float* __restrict__ C) {
  __shared__ __attribute__((aligned(128))) char lds[131072];

  const int tid = threadIdx.x;
  const int lane = tid & 63;
  const int wm = (tid >> 6) >> 2;   // 0..1
  const int wn = (tid >> 6) & 3;    // 0..3
  const int lr = lane & 15;

  const int bid = blockIdx.x;                    // nwg = 512 = 8 * 64, bijective
  const int swz = (bid & 7) * 64 + (bid >> 3);
  const int bm = swz >> 4;                       // 0..31
  const int bn = swz & 15;                       // 0..15

  const unsigned short* Bp = B + (size_t)bn * BN * K_TOT;

  // A f32 reg-staging constants
  const int arow = tid >> 1;                     // 0..255
  const int akh  = tid & 1;                      // k-half (32 f32)
  const float* Axp = X + ((size_t)(bm * BM + arow)) * K_TOT + akh * 32;
  const int aswz = (arow & 7) << 4;
  const int aldsrow = arow * 128;

  // B staging: 512 thr x 16B = 64 rows/issue, 2 issues per 128-row half
  const int srow = tid >> 3;                              // 0..63
  const int sgcol = (((tid & 7) * 16) ^ ((srow & 7) << 4)) >> 1;  // elem col (inv swizzle)
  const int wavebase = (tid & 448) << 4;                  // wave-uniform LDS base part

  // fragment-read constants (swizzled byte cols for k-halves 0/1)
  const int cs0 = (((lane >> 4) << 4)) ^ ((lr & 7) << 4);
  const int cs1 = (64 + ((lane >> 4) << 4)) ^ ((lr & 7) << 4);
  const int rowA0 = (wm * 128 + lr) * 128;          // byte base of A frags
  const int rowB0 = 32768 + (wn * 64 + lr) * 128;   // byte base of B frags

#define RD(off) (*(const bf16x8*)(lds + (off)))
#define STAGE(GB, TK, RB, LOFF)                                               \
  { _Pragma("unroll")                                                         \
    for (int ii = 0; ii < 2; ++ii) {                                          \
      GLDS16((GB) + (size_t)((RB) + ii * 64 + srow) * K_TOT + (TK) + sgcol,   \
             lds + (LOFF) + ii * 8192 + wavebase);                            \
    } }
#define BARRIER()                       \
  {                                     \
    asm volatile("" ::: "memory");      \
    __builtin_amdgcn_s_barrier();       \
    asm volatile("" ::: "memory");      \
  }

#define ALOADF(KOFF)                                                          \
  { _Pragma("unroll") for (int q = 0; q < 8; ++q)                             \
      af32[q] = *(const f32x4*)(Axp + (KOFF) + q * 4); }

#define ACVTW(LOFF)                                                           \
  { _Pragma("unroll") for (int j = 0; j < 4; ++j) {                           \
      u16x8 w;                                                                \
      _Pragma("unroll") for (int e = 0; e < 8; ++e)                           \
        w[e] = f2bf(af32[j * 2 + (e >> 2)][e & 3]);                           \
      *(u16x8*)(lds + (LOFF) + aldsrow + ((akh * 64 + j * 16) ^ aswz)) = w;   \
    } }

// 16 MFMA for quadrant (m-half MH, one k-half): 4 A-frags x 4 B-frags
#define MFMA_Q(MH, AV, BV)                                                    \
  { __builtin_amdgcn_s_setprio(1);                                            \
    _Pragma("unroll")                                                         \
    for (int r = 0; r < 4; ++r) {                                             \
      _Pragma("unroll")                                                       \
      for (int nf = 0; nf < 4; ++nf)                                          \
        acc[(MH) * 4 + r][nf] = __builtin_amdgcn_mfma_f32_16x16x32_bf16(      \
            AV[r], BV[nf], acc[(MH) * 4 + r][nf], 0, 0, 0);                   \
    }                                                                         \
    __builtin_amdgcn_s_setprio(0); }

#define TILE(T, BO, STG_A, STG_B, VMF, LAST)                                      \
  {                                                                               \
    bf16x8 Aa[4], Ab[4], Ac[4], Ad[4], Bx[4], By[4];                              \
    f32x4 af32[8];                                                                \
    if (STG_A) ALOADF(((T) + 1) * BK);                                            \
    _Pragma("unroll") for (int r = 0; r < 4; ++r)                                 \
        Aa[r] = RD((BO) + rowA0 + r * 2048 + cs0);                                \
    _Pragma("unroll") for (int n = 0; n < 4; ++n)                                 \
        Bx[n] = RD((BO) + rowB0 + n * 2048 + cs0);                                \
    _Pragma("unroll") for (int r = 0; r < 4; ++r)                                 \
        Ab[r] = RD((BO) + rowA0 + (4 + r) * 2048 + cs0);                          \
    MFMA_Q(0, Aa, Bx);                                                            \
    _Pragma("unroll") for (int r = 0; r < 4; ++r)                                 \
        Ac[r] = RD((BO) + rowA0 + r * 2048 + cs1);                                \
    _Pragma("unroll") for (int n = 0; n < 4; ++n)                                 \
        By[n] = RD((BO) + rowB0 + n * 2048 + cs1);                                \
    MFMA_Q(1, Ab, Bx);                                                            \
    asm volatile("s_waitcnt lgkmcnt(0)" ::: "memory");                            \
    BARRIER();                                                                    \
    if (STG_B) STAGE(Bp, ((T) + 2) * BK, 0, (BO) + 32768);                        \
    if (STG_A) {                                                                  \
      asm volatile("s_waitcnt vmcnt(" VMF ")" ::: "memory");                      \
      ACVTW((BO) ^ 65536);                                                        \
    }                                                                             \
    if (STG_B) STAGE(Bp, ((T) + 2) * BK, 128, (BO) + 49152);                      \
    _Pragma("unroll") for (int r = 0; r < 4; ++r)                                 \
        Ad[r] = RD((BO) + rowA0 + (4 + r) * 2048 + cs1);                          \
    MFMA_Q(0, Ac, By);                                                            \
    MFMA_Q(1, Ad, By);                                                            \
    if (!(LAST)) {                                                                \
      asm volatile("s_waitcnt lgkmcnt(0)" ::: "memory");                          \
      BARRIER();                                                                  \
    }                                                                             \
  }

  f32x4 acc[8][4] = {};

  // ---- prologue: A(0) f32 loads; stage B(0), B(1); cvt+write A(0) ----
  {
    f32x4 af32[8];
    ALOADF(0);
    STAGE(Bp, 0, 0, 32768);
    STAGE(Bp, 0, 128, 49152);
    STAGE(Bp, BK, 0, 65536 + 32768);
    STAGE(Bp, BK, 128, 65536 + 49152);
    asm volatile("s_waitcnt vmcnt(8)" ::: "memory");   // A(0) regs ready
    ACVTW(0);
    asm volatile("s_waitcnt vmcnt(4)" ::: "memory");   // B(0) landed; B(1) in flight
    asm volatile("s_waitcnt lgkmcnt(0)" ::: "memory"); // A(0) writes visible
    BARRIER();
  }

  // main loop: tiles 0..NT-3 steady (vmcnt(2)); NT-2 drains A (vmcnt(0)); NT-1 tail
  for (int t = 0; t < NT - 2; t += 2) {
    TILE(t,     0,     1, 1, "2", 0);
    TILE(t + 1, 65536, 1, 1, "2", 0);
  }
  TILE(NT - 2, 0,     1, 0, "0", 0);
  TILE(NT - 1, 65536, 0, 0, "0", 1);

  // ---- epilogue: C = acc + bias ----
  const int lg4 = (lane >> 4) << 2;
#pragma unroll
  for (int nf = 0; nf < 4; ++nf) {
    const int col = bn * BN + wn * 64 + nf * 16 + lr;
    const float bv = bias[col];
#pragma unroll
    for (int mf = 0; mf < 8; ++mf) {
      const int row0 = bm * BM + wm * 128 + mf * 16 + lg4;
      float* cp = C + (size_t)row0 * N_TOT + col;
#pragma unroll
      for (int j = 0; j < 4; ++j) cp[(size_t)j * N_TOT] = acc[mf][nf][j] + bv;
    }
  }
#undef RD
#undef STAGE
#undef BARRIER
#undef ALOADF
#undef ACVTW
#undef MFMA_Q
#undef TILE
}

extern "C" void kernel_launch(void* const* d_in, const int* in_sizes, int n_in,
                              void* d_out, int out_size, void* d_ws, size_t ws_size,
                              hipStream_t stream) {
  const float* x    = (const float*)d_in[0];   // [4,2048,4096] f32
  const float* cb   = (const float*)d_in[1];   // [4096,256]   f32
  const float* bias = (const float*)d_in[2];   // [4096]       f32
  const int*   idx  = (const int*)d_in[3];     // [4096,4096]  int

  float* out = (float*)d_out;                  // [4,2048,4096] f32

  unsigned short* Wb = (unsigned short*)d_ws;  // 32 MB (X no longer staged)

  // W dequant only: 16.7M weights / (8 * 256) = 8192 blocks
  prep<<<8192, 256, 0, stream>>>(cb, idx, Wb);
  // (8192/256) * (4096/256) = 32*16 = 512 blocks, 512 threads
  gemm8<<<512, 512, 0, stream>>>(x, Wb, bias, out);
}

// Round 12
// 275.705 us; speedup vs baseline: 1.7695x; 1.7695x over previous
//
#include <hip/hip_runtime.h>

typedef __bf16 bf16x8 __attribute__((ext_vector_type(8)));
typedef float f32x4 __attribute__((ext_vector_type(4)));
typedef unsigned short u16x8 __attribute__((ext_vector_type(8)));
typedef int i32x4 __attribute__((ext_vector_type(4)));

#define M_TOT 8192
#define K_TOT 4096
#define N_TOT 4096
#define BM 256
#define BN 256
#define BK 64
#define NT (K_TOT / BK)   // 64

__device__ __forceinline__ unsigned short f2bf(float f) {
  union { float f; unsigned int u; } v; v.f = f;
  unsigned int u = v.u;
  return (unsigned short)((u + 0x7FFFu + ((u >> 16) & 1u)) >> 16);  // RNE
}

// weight[o][i] = bf16(codebook[o, indices[o,i]]); grid-stride, 8 elems/thread/iter
__global__ __launch_bounds__(256) void deq_w(const float* __restrict__ cb,
                                             const int* __restrict__ idx,
                                             unsigned short* __restrict__ Wb) {
  const size_t stride = (size_t)gridDim.x * 256 * 8;
  for (size_t base = ((size_t)blockIdx.x * 256 + threadIdx.x) * 8;
       base < (size_t)N_TOT * K_TOT; base += stride) {
    const float* crow = cb + ((base >> 12) << 8);  // row = base/4096, 256 floats/row
    i32x4 i0 = *(const i32x4*)(idx + base);
    i32x4 i1 = *(const i32x4*)(idx + base + 4);
    u16x8 o;
#pragma unroll
    for (int j = 0; j < 4; ++j) { o[j] = f2bf(crow[i0[j]]); o[4 + j] = f2bf(crow[i1[j]]); }
    *(u16x8*)(Wb + base) = o;
  }
}

// x f32 -> bf16; grid-stride
__global__ __launch_bounds__(256) void conv_x(const float* __restrict__ X,
                                              unsigned short* __restrict__ Xc) {
  const size_t stride = (size_t)gridDim.x * 256 * 8;
  for (size_t base = ((size_t)blockIdx.x * 256 + threadIdx.x) * 8;
       base < (size_t)M_TOT * K_TOT; base += stride) {
    f32x4 a = *(const f32x4*)(X + base);
    f32x4 b = *(const f32x4*)(X + base + 4);
    u16x8 o;
#pragma unroll
    for (int j = 0; j < 4; ++j) { o[j] = f2bf(a[j]); o[4 + j] = f2bf(b[j]); }
    *(u16x8*)(Xc + base) = o;
  }
}

#define GLDS16(g, l)                                                      \
  __builtin_amdgcn_global_load_lds(                                       \
      (__attribute__((address_space(1))) void*)(g),                       \
      (__attribute__((address_space(3))) void*)(l), 16, 0, 0)

// ============================================================================
// EXACT R4 structure (measured optimum: 227.5 us, MfmaUtil 54.5, 0 conflicts).
// 256x256 tile, BK=64, 8 waves (2M x 4N), double-buffered 128KB LDS.
// Two barriers per K-tile; ds_reads pipelined under MFMA at register level.
// Quadrant phases (m-half x k-half):
//   p0 = (mh0,kh0): Aa x Bx    p1 = (mh1,kh0): Ab x Bx
//   p2 = (mh0,kh1): Ac x By    p3 = (mh1,kh1): Ad x By
// Mid-tile lgkm0+barrier gates B(t+2) staging into the current B region.
// End-of-tile counted vmcnt(4) retires B(t+1)+A(t+1), leaves B(t+2) in
// flight. Stages per tile t: A(t+1)h0,h1 early; B(t+2)h0,h1 after mid-bar.
// ============================================================================
__global__ __launch_bounds__(512, 2) void gemm8(const unsigned short* __restrict__ A,
                                                const unsigned short* __restrict__ B,
                                                const float* __restrict__ bias,
                                                float* __restrict__ C) {
  __shared__ __attribute__((aligned(128))) char lds[131072];

  const int tid = threadIdx.x;
  const int lane = tid & 63;
  const int wm = (tid >> 6) >> 2;   // 0..1
  const int wn = (tid >> 6) & 3;    // 0..3
  const int lr = lane & 15;

  const int bid = blockIdx.x;                    // nwg = 512 = 8 * 64, bijective
  const int swz = (bid & 7) * 64 + (bid >> 3);
  const int bm = swz >> 4;                       // 0..31
  const int bn = swz & 15;                       // 0..15

  const unsigned short* Ap = A + (size_t)bm * BM * K_TOT;
  const unsigned short* Bp = B + (size_t)bn * BN * K_TOT;

  // staging: 512 thr x 16B = 64 rows/issue, 2 issues per 128-row half
  const int srow = tid >> 3;                              // 0..63
  const int sgcol = (((tid & 7) * 16) ^ ((srow & 7) << 4)) >> 1;  // elem col (inv swizzle)
  const int wavebase = (tid & 448) << 4;                  // wave-uniform LDS base part

  // fragment-read constants (swizzled byte cols for k-halves 0/1)
  const int cs0 = (((lane >> 4) << 4)) ^ ((lr & 7) << 4);
  const int cs1 = (64 + ((lane >> 4) << 4)) ^ ((lr & 7) << 4);
  const int rowA0 = (wm * 128 + lr) * 128;          // byte base of A frags
  const int rowB0 = 32768 + (wn * 64 + lr) * 128;   // byte base of B frags

#define RD(off) (*(const bf16x8*)(lds + (off)))
#define STAGE(GB, TK, RB, LOFF)                                               \
  { _Pragma("unroll")                                                         \
    for (int ii = 0; ii < 2; ++ii) {                                          \
      GLDS16((GB) + (size_t)((RB) + ii * 64 + srow) * K_TOT + (TK) + sgcol,   \
             lds + (LOFF) + ii * 8192 + wavebase);                            \
    } }
#define BARRIER()                       \
  {                                     \
    asm volatile("" ::: "memory");      \
    __builtin_amdgcn_s_barrier();       \
    asm volatile("" ::: "memory");      \
  }

// 16 MFMA for quadrant (m-half MH, one k-half): 4 A-frags x 4 B-frags
#define MFMA_Q(MH, AV, BV)                                                    \
  { __builtin_amdgcn_s_setprio(1);                                            \
    _Pragma("unroll")                                                         \
    for (int r = 0; r < 4; ++r) {                                             \
      _Pragma("unroll")                                                       \
      for (int nf = 0; nf < 4; ++nf)                                          \
        acc[(MH) * 4 + r][nf] = __builtin_amdgcn_mfma_f32_16x16x32_bf16(      \
            AV[r], BV[nf], acc[(MH) * 4 + r][nf], 0, 0, 0);                   \
    }                                                                         \
    __builtin_amdgcn_s_setprio(0); }

#define TILE(T, BO, STG_A, STG_B, VMF, DO_BAR)                                    \
  {                                                                               \
    bf16x8 Aa[4], Ab[4], Ac[4], Ad[4], Bx[4], By[4];                              \
    _Pragma("unroll") for (int r = 0; r < 4; ++r)                                 \
        Aa[r] = RD((BO) + rowA0 + r * 2048 + cs0);                                \
    _Pragma("unroll") for (int n = 0; n < 4; ++n)                                 \
        Bx[n] = RD((BO) + rowB0 + n * 2048 + cs0);                                \
    if (STG_A) STAGE(Ap, ((T) + 1) * BK, 0, ((BO) ^ 65536) + 0);                  \
    _Pragma("unroll") for (int r = 0; r < 4; ++r)                                 \
        Ab[r] = RD((BO) + rowA0 + (4 + r) * 2048 + cs0);                          \
    if (STG_A) STAGE(Ap, ((T) + 1) * BK, 128, ((BO) ^ 65536) + 16384);            \
    MFMA_Q(0, Aa, Bx);                                                            \
    _Pragma("unroll") for (int r = 0; r < 4; ++r)                                 \
        Ac[r] = RD((BO) + rowA0 + r * 2048 + cs1);                                \
    _Pragma("unroll") for (int n = 0; n < 4; ++n)                                 \
        By[n] = RD((BO) + rowB0 + n * 2048 + cs1);                                \
    MFMA_Q(1, Ab, Bx);                                                            \
    asm volatile("s_waitcnt lgkmcnt(0)" ::: "memory");                            \
    BARRIER();                                                                    \
    if (STG_B) STAGE(Bp, ((T) + 2) * BK, 0, (BO) + 32768);                        \
    if (STG_B) STAGE(Bp, ((T) + 2) * BK, 128, (BO) + 49152);                      \
    _Pragma("unroll") for (int r = 0; r < 4; ++r)                                 \
        Ad[r] = RD((BO) + rowA0 + (4 + r) * 2048 + cs1);                          \
    MFMA_Q(0, Ac, By);                                                            \
    MFMA_Q(1, Ad, By);                                                            \
    asm volatile("s_waitcnt vmcnt(" VMF ")" ::: "memory");                        \
    if (DO_BAR) BARRIER();                                                        \
  }

  f32x4 acc[8][4] = {};

  // ---- prologue: stage B(0), A(0), B(1); retire B(0)+A(0); B(1) in flight ----
  STAGE(Bp, 0, 0, 32768);
  STAGE(Bp, 0, 128, 49152);
  STAGE(Ap, 0, 0, 0);
  STAGE(Ap, 0, 128, 16384);
  STAGE(Bp, BK, 0, 65536 + 32768);
  STAGE(Bp, BK, 128, 65536 + 49152);
  asm volatile("s_waitcnt vmcnt(4)" ::: "memory");
  BARRIER();

  // main loop: tiles 0..NT-3 fully pipelined; last two tiles specialized
  for (int t = 0; t < NT - 2; t += 2) {
    TILE(t,     0,     1, 1, "4", 1);
    TILE(t + 1, 65536, 1, 1, "4", 1);
  }
  TILE(NT - 2, 0,     1, 0, "0", 1);
  TILE(NT - 1, 65536, 0, 0, "0", 0);

  // ---- epilogue: C = acc + bias ----
  const int lg4 = (lane >> 4) << 2;
#pragma unroll
  for (int nf = 0; nf < 4; ++nf) {
    const int col = bn * BN + wn * 64 + nf * 16 + lr;
    const float bv = bias[col];
#pragma unroll
    for (int mf = 0; mf < 8; ++mf) {
      const int row0 = bm * BM + wm * 128 + mf * 16 + lg4;
      float* cp = C + (size_t)row0 * N_TOT + col;
#pragma unroll
      for (int j = 0; j < 4; ++j) cp[(size_t)j * N_TOT] = acc[mf][nf][j] + bv;
    }
  }
#undef RD
#undef STAGE
#undef BARRIER
#undef MFMA_Q
#undef TILE
}

extern "C" void kernel_launch(void* const* d_in, const int* in_sizes, int n_in,
                              void* d_out, int out_size, void* d_ws, size_t ws_size,
                              hipStream_t stream) {
  const float* x    = (const float*)d_in[0];   // [4,2048,4096] f32
  const float* cb   = (const float*)d_in[1];   // [4096,256]   f32
  const float* bias = (const float*)d_in[2];   // [4096]       f32
  const int*   idx  = (const int*)d_in[3];     // [4096,4096]  int

  float* out = (float*)d_out;                  // [4,2048,4096] f32

  unsigned short* Wb = (unsigned short*)d_ws;                                      // 32 MB
  unsigned short* Xc = (unsigned short*)((char*)d_ws + (size_t)N_TOT * K_TOT * 2); // 64 MB

  // grid-stride prep (Guideline 11: ~2048 blocks, loop the rest)
  deq_w<<<2048, 256, 0, stream>>>(cb, idx, Wb);
  conv_x<<<2048, 256, 0, stream>>>(x, Xc);
  // (8192/256) * (4096/256) = 32*16 = 512 blocks, 512 threads
  gemm8<<<512, 512, 0, stream>>>(Xc, Wb, bias, out);
}